// Round 1
// baseline (20764.848 us; speedup 1.0000x reference)
//
#include <hip/hip_runtime.h>
#include <math.h>

#define HID 1024
#define SEQ 4096
#define NWG 64        // workgroups in the persistent RNN kernel (<= 256 CUs, always co-resident)
#define BT  8         // t-tile for the U GEMM

// ---------------------------------------------------------------------------
// Device-wide barrier: monotonic counter in d_ws (zeroed via hipMemsetAsync
// each launch). Release-add + relaxed spin + acquire fence gives cross-XCD
// visibility (agent-scope release emits buffer_wbl2, acquire emits buffer_inv).
// ---------------------------------------------------------------------------
__device__ __forceinline__ void grid_barrier(unsigned* cnt, unsigned target) {
  __syncthreads();                       // all waves' stores issued (waitcnt vmcnt before barrier)
  if (threadIdx.x == 0) {
    __hip_atomic_fetch_add(cnt, 1u, __ATOMIC_RELEASE, __HIP_MEMORY_SCOPE_AGENT);
    while (__hip_atomic_load(cnt, __ATOMIC_RELAXED, __HIP_MEMORY_SCOPE_AGENT) < target) {
      __builtin_amdgcn_s_sleep(1);
    }
    __builtin_amdgcn_fence(__ATOMIC_ACQUIRE, "agent");  // invalidate L1/L2 so h reads are fresh
  }
  __syncthreads();
}

// ---------------------------------------------------------------------------
// Phase 1+2 fused: embedding gather + L2 normalize + U = emb @ W_hi^T + b
// Grid: SEQ/BT = 512 blocks x 256 threads. LDS: 8x256 float4 = 32 KB.
// Trick: GEMM on RAW embedding rows, scale acc by 1/norm_t at the end
// (normalization is a per-row scalar).
// ---------------------------------------------------------------------------
__global__ void __launch_bounds__(256) embed_gemm(
    const int* __restrict__ src, const float* __restrict__ W,
    const float* __restrict__ Whi, const float* __restrict__ bias,
    float* __restrict__ U) {
  __shared__ float4 se[BT][256];   // raw embedding tile
  __shared__ float  sw[BT][4];     // per-row sum-of-squares partials (per wave)

  const int tid  = threadIdx.x;
  const int wv   = tid >> 6;
  const int lane = tid & 63;
  const int t0   = blockIdx.x * BT;

  // stage raw rows + per-row sum of squares
  #pragma unroll
  for (int i = 0; i < BT; i++) {
    const int idx = src[t0 + i];
    float4 v = ((const float4*)(W + (size_t)idx * HID))[tid];
    se[i][tid] = v;
    float ss = v.x*v.x + v.y*v.y + v.z*v.z + v.w*v.w;
    ss += __shfl_xor(ss, 1);  ss += __shfl_xor(ss, 2);  ss += __shfl_xor(ss, 4);
    ss += __shfl_xor(ss, 8);  ss += __shfl_xor(ss, 16); ss += __shfl_xor(ss, 32);
    if (lane == 0) sw[i][wv] = ss;
  }
  __syncthreads();

  float inv_norm[BT];
  #pragma unroll
  for (int i = 0; i < BT; i++) {
    float n = sw[i][0] + sw[i][1] + sw[i][2] + sw[i][3];
    inv_norm[i] = 1.0f / fmaxf(sqrtf(n), 1e-12f);
  }

  // GEMM: thread owns j = tid + q*256 (q=0..3); acc over k with float4 steps
  float acc[BT][4];
  #pragma unroll
  for (int i = 0; i < BT; i++)
    #pragma unroll
    for (int q = 0; q < 4; q++) acc[i][q] = 0.0f;

  for (int k4 = 0; k4 < HID / 4; k4++) {
    float4 wr[4];
    #pragma unroll
    for (int q = 0; q < 4; q++)
      wr[q] = *(const float4*)(Whi + (size_t)(tid + q * 256) * HID + k4 * 4);
    #pragma unroll
    for (int i = 0; i < BT; i++) {
      float4 e = se[i][k4];    // broadcast, conflict-free
      #pragma unroll
      for (int q = 0; q < 4; q++)
        acc[i][q] += wr[q].x*e.x + wr[q].y*e.y + wr[q].z*e.z + wr[q].w*e.w;
    }
  }

  #pragma unroll
  for (int i = 0; i < BT; i++) {
    #pragma unroll
    for (int q = 0; q < 4; q++) {
      const int j = tid + q * 256;
      U[(size_t)(t0 + i) * HID + j] = acc[i][q] * inv_norm[i] + bias[j];
    }
  }
}

// ---------------------------------------------------------------------------
// Phase 3: persistent sequential RNN. W_hh lives in registers:
//   global wave gw (256 waves) owns rows j = gw*4 + jj (jj = lane>>4),
//   16 lanes per row each hold 64 k-weights (16 float4). Full dot product
//   reduces intra-wave with 4 shfl_xor. h rows live in d_out itself.
// ---------------------------------------------------------------------------
__global__ void __launch_bounds__(256) rnn_seq(
    const float* __restrict__ Whh, const float* __restrict__ U,
    const float* __restrict__ h0, float* __restrict__ out,
    unsigned* __restrict__ cnt) {
  const int tid  = threadIdx.x;
  const int lane = tid & 63;
  const int kk   = lane & 15;
  const int jj   = lane >> 4;
  const int gw   = blockIdx.x * 4 + (tid >> 6);
  const int j    = gw * 4 + jj;
  const int k0   = kk * 64;

  // load this thread's 64 W_hh weights into registers (one-time)
  float4 w[16];
  const float4* wp = (const float4*)(Whh + (size_t)j * HID + k0);
  #pragma unroll
  for (int i = 0; i < 16; i++) w[i] = wp[i];

  // out row 0 = h0
  if (blockIdx.x == 0) ((float4*)out)[tid] = ((const float4*)h0)[tid];

  unsigned target = NWG;
  grid_barrier(cnt, target);

  #pragma unroll 1
  for (int t = 0; t < SEQ; t++) {
    const float4* hp = (const float4*)(out + (size_t)t * HID + k0);
    float a0 = 0.f, a1 = 0.f, a2 = 0.f, a3 = 0.f;
    #pragma unroll
    for (int i = 0; i < 16; i += 4) {
      float4 h0v = hp[i + 0], h1v = hp[i + 1], h2v = hp[i + 2], h3v = hp[i + 3];
      a0 += w[i+0].x*h0v.x + w[i+0].y*h0v.y + w[i+0].z*h0v.z + w[i+0].w*h0v.w;
      a1 += w[i+1].x*h1v.x + w[i+1].y*h1v.y + w[i+1].z*h1v.z + w[i+1].w*h1v.w;
      a2 += w[i+2].x*h2v.x + w[i+2].y*h2v.y + w[i+2].z*h2v.z + w[i+2].w*h2v.w;
      a3 += w[i+3].x*h3v.x + w[i+3].y*h3v.y + w[i+3].z*h3v.z + w[i+3].w*h3v.w;
    }
    float y = (a0 + a1) + (a2 + a3);
    y += __shfl_xor(y, 1);
    y += __shfl_xor(y, 2);
    y += __shfl_xor(y, 4);
    y += __shfl_xor(y, 8);      // all 16 lanes of the row group now hold the full dot

    const float u  = U[(size_t)t * HID + j];   // broadcast within row group
    const float hn = tanhf(y + u);
    if (kk == 0) out[(size_t)(t + 1) * HID + j] = hn;

    target += NWG;
    grid_barrier(cnt, target);
  }
}

// ---------------------------------------------------------------------------
extern "C" void kernel_launch(void* const* d_in, const int* in_sizes, int n_in,
                              void* d_out, int out_size, void* d_ws, size_t ws_size,
                              hipStream_t stream) {
  const int*   src = (const int*)  d_in[0];
  const float* W   = (const float*)d_in[1];
  const float* h0  = (const float*)d_in[2];
  const float* Whi = (const float*)d_in[3];
  const float* Whh = (const float*)d_in[4];
  const float* b   = (const float*)d_in[5];
  float* out = (float*)d_out;

  float*    U   = (float*)d_ws;                                  // 16 MB
  unsigned* cnt = (unsigned*)((char*)d_ws + (size_t)SEQ * HID * sizeof(float));

  hipMemsetAsync(cnt, 0, 64, stream);                            // barrier counter = 0
  embed_gemm<<<SEQ / BT, 256, 0, stream>>>(src, W, Whi, b, U);
  rnn_seq<<<NWG, 256, 0, stream>>>(Whh, U, h0, out, cnt);
}

// Round 2
// 14052.605 us; speedup vs baseline: 1.4777x; 1.4777x over previous
//
#include <hip/hip_runtime.h>
#include <math.h>

#define HID 1024
#define SEQ 4096
#define NWG 64        // 64 WGs x 256 thr = 256 waves; always co-resident on 256 CUs
#define BT  8         // t-tile for the U GEMM

typedef float v4f __attribute__((ext_vector_type(4)));

// ---------------------------------------------------------------------------
// Phase 1+2 fused: embedding gather + L2 normalize + U = emb @ W_hi^T + b
// (unchanged from R1 — correctness-proven, ~0.6 ms)
// ---------------------------------------------------------------------------
__global__ void __launch_bounds__(256) embed_gemm(
    const int* __restrict__ src, const float* __restrict__ W,
    const float* __restrict__ Whi, const float* __restrict__ bias,
    float* __restrict__ U) {
  __shared__ float4 se[BT][256];
  __shared__ float  sw[BT][4];

  const int tid  = threadIdx.x;
  const int wv   = tid >> 6;
  const int lane = tid & 63;
  const int t0   = blockIdx.x * BT;

  #pragma unroll
  for (int i = 0; i < BT; i++) {
    const int idx = src[t0 + i];
    float4 v = ((const float4*)(W + (size_t)idx * HID))[tid];
    se[i][tid] = v;
    float ss = v.x*v.x + v.y*v.y + v.z*v.z + v.w*v.w;
    ss += __shfl_xor(ss, 1);  ss += __shfl_xor(ss, 2);  ss += __shfl_xor(ss, 4);
    ss += __shfl_xor(ss, 8);  ss += __shfl_xor(ss, 16); ss += __shfl_xor(ss, 32);
    if (lane == 0) sw[i][wv] = ss;
  }
  __syncthreads();

  float inv_norm[BT];
  #pragma unroll
  for (int i = 0; i < BT; i++) {
    float n = sw[i][0] + sw[i][1] + sw[i][2] + sw[i][3];
    inv_norm[i] = 1.0f / fmaxf(sqrtf(n), 1e-12f);
  }

  float acc[BT][4];
  #pragma unroll
  for (int i = 0; i < BT; i++)
    #pragma unroll
    for (int q = 0; q < 4; q++) acc[i][q] = 0.0f;

  for (int k4 = 0; k4 < HID / 4; k4++) {
    float4 wr[4];
    #pragma unroll
    for (int q = 0; q < 4; q++)
      wr[q] = *(const float4*)(Whi + (size_t)(tid + q * 256) * HID + k4 * 4);
    #pragma unroll
    for (int i = 0; i < BT; i++) {
      float4 e = se[i][k4];
      #pragma unroll
      for (int q = 0; q < 4; q++)
        acc[i][q] += wr[q].x*e.x + wr[q].y*e.y + wr[q].z*e.z + wr[q].w*e.w;
    }
  }

  #pragma unroll
  for (int i = 0; i < BT; i++) {
    #pragma unroll
    for (int q = 0; q < 4; q++) {
      const int j = tid + q * 256;
      U[(size_t)(t0 + i) * HID + j] = acc[i][q] * inv_norm[i] + bias[j];
    }
  }
}

// ---------------------------------------------------------------------------
// Phase 3: persistent RNN with data-as-flag synchronization.
// 256 independent waves; wave gw owns rows gw*4..gw*4+3. Per step, each wave
// publishes its 4 h-values as ONE sc0/sc1 dwordx4 into a 4-slot rotating
// tagged buffer (value = h + B, B = 2 + 4*((row>>2)&1)). Consumers spin on
// bypassing (sc0/sc1) loads of the tagged data; the window check doubles as
// the readiness flag AND torn-write protection (per-dword: a stale/partial
// chunk has components in the other generation's window -> rejected).
// No atomics, no fences, no barriers, no cache maintenance in the loop.
// Slot-reuse safety: a producer can only write row r+4 after consuming rows
// r..r+3, and row r was consumed (hence LLC-visible) device-wide before any
// wave could compute row r+2 — so the overwrite is always of dead data.
// ---------------------------------------------------------------------------
__global__ void __launch_bounds__(256) rnn_seq(
    const float* __restrict__ Whh, const float* __restrict__ U,
    const float* __restrict__ h0, float* __restrict__ out,
    float* __restrict__ hbuf) {
  const int tid  = threadIdx.x;
  const int lane = tid & 63;
  const int kk   = lane & 15;          // k-group: this thread covers k = kk*4 + i*64
  const int gw   = blockIdx.x * 4 + (tid >> 6);
  const int j    = gw * 4 + (lane >> 4);   // output row owned by this lane

  // W_hh fragment (registers): w[i] = Whh[j][i*64 + kk*4 .. +3]; S = sum of all 64
  v4f w[16];
  float S = 0.0f;
  {
    const v4f* wp = (const v4f*)(Whh + (size_t)j * HID + kk * 4);
    #pragma unroll
    for (int i = 0; i < 16; i++) {
      w[i] = wp[i * 16];
      S += w[i].x + w[i].y + w[i].z + w[i].w;
    }
  }

  // publish row 0 (slot 0, window base 2.0) + raw row 0 to out
  if (lane == 0) {
    v4f r0 = *(const v4f*)(h0 + gw * 4);
    *(v4f*)(out + gw * 4) = r0;
    v4f t0 = r0 + 2.0f;
    const float* dst = hbuf + gw * 4;
    asm volatile("global_store_dwordx4 %0, %1, off sc0 sc1"
                 :: "v"(dst), "v"(t0) : "memory");
  }

  #pragma unroll 1
  for (int t = 0; t < SEQ; t++) {
    const float u  = U[(size_t)t * HID + j];                 // h-independent: overlaps the spin
    const float Bc = 2.0f + 4.0f * (float)((t >> 2) & 1);    // window base for row t
    const float* src = hbuf + ((t & 3) << 10) + kk * 4;      // slot base + this thread's offset

    v4f h[16];
    for (;;) {
      asm volatile(
        "global_load_dwordx4 %0,  %16, off sc0 sc1\n\t"
        "global_load_dwordx4 %1,  %16, off offset:256  sc0 sc1\n\t"
        "global_load_dwordx4 %2,  %16, off offset:512  sc0 sc1\n\t"
        "global_load_dwordx4 %3,  %16, off offset:768  sc0 sc1\n\t"
        "global_load_dwordx4 %4,  %16, off offset:1024 sc0 sc1\n\t"
        "global_load_dwordx4 %5,  %16, off offset:1280 sc0 sc1\n\t"
        "global_load_dwordx4 %6,  %16, off offset:1536 sc0 sc1\n\t"
        "global_load_dwordx4 %7,  %16, off offset:1792 sc0 sc1\n\t"
        "global_load_dwordx4 %8,  %16, off offset:2048 sc0 sc1\n\t"
        "global_load_dwordx4 %9,  %16, off offset:2304 sc0 sc1\n\t"
        "global_load_dwordx4 %10, %16, off offset:2560 sc0 sc1\n\t"
        "global_load_dwordx4 %11, %16, off offset:2816 sc0 sc1\n\t"
        "global_load_dwordx4 %12, %16, off offset:3072 sc0 sc1\n\t"
        "global_load_dwordx4 %13, %16, off offset:3328 sc0 sc1\n\t"
        "global_load_dwordx4 %14, %16, off offset:3584 sc0 sc1\n\t"
        "global_load_dwordx4 %15, %16, off offset:3840 sc0 sc1\n\t"
        "s_waitcnt vmcnt(0)"
        : "=&v"(h[0]),  "=&v"(h[1]),  "=&v"(h[2]),  "=&v"(h[3]),
          "=&v"(h[4]),  "=&v"(h[5]),  "=&v"(h[6]),  "=&v"(h[7]),
          "=&v"(h[8]),  "=&v"(h[9]),  "=&v"(h[10]), "=&v"(h[11]),
          "=&v"(h[12]), "=&v"(h[13]), "=&v"(h[14]), "=&v"(h[15])
        : "v"(src)
        : "memory");

      bool ok = true;
      #pragma unroll
      for (int i = 0; i < 16; i++) {
        v4f d = h[i] - Bc;
        float m = fmaxf(fmaxf(fabsf(d.x), fabsf(d.y)),
                        fmaxf(fabsf(d.z), fabsf(d.w)));
        ok = ok && (m < 1.5f);
      }
      if (__all(ok)) break;
    }

    // dot product on biased values; de-bias with -Bc*S
    float a0 = 0.f, a1 = 0.f, a2 = 0.f, a3 = 0.f;
    #pragma unroll
    for (int i = 0; i < 16; i += 4) {
      a0 += w[i+0].x*h[i+0].x + w[i+0].y*h[i+0].y + w[i+0].z*h[i+0].z + w[i+0].w*h[i+0].w;
      a1 += w[i+1].x*h[i+1].x + w[i+1].y*h[i+1].y + w[i+1].z*h[i+1].z + w[i+1].w*h[i+1].w;
      a2 += w[i+2].x*h[i+2].x + w[i+2].y*h[i+2].y + w[i+2].z*h[i+2].z + w[i+2].w*h[i+2].w;
      a3 += w[i+3].x*h[i+3].x + w[i+3].y*h[i+3].y + w[i+3].z*h[i+3].z + w[i+3].w*h[i+3].w;
    }
    float y = ((a0 + a1) + (a2 + a3)) - Bc * S;
    y += __shfl_xor(y, 1);
    y += __shfl_xor(y, 2);
    y += __shfl_xor(y, 4);
    y += __shfl_xor(y, 8);

    const float hn = tanhf(y + u);

    // gather the wave's 4 row values into a float4 and publish
    v4f hv;
    hv.x = __shfl(hn, 0);
    hv.y = __shfl(hn, 16);
    hv.z = __shfl(hn, 32);
    hv.w = __shfl(hn, 48);

    if (lane == 0) {
      *(v4f*)(out + (size_t)(t + 1) * HID + gw * 4) = hv;    // raw output (plain store)
      const float Bp = 2.0f + 4.0f * (float)(((t + 1) >> 2) & 1);
      v4f tv = hv + Bp;
      const float* dst = hbuf + (((t + 1) & 3) << 10) + gw * 4;
      asm volatile("global_store_dwordx4 %0, %1, off sc0 sc1"
                   :: "v"(dst), "v"(tv) : "memory");
    }
  }
}

// ---------------------------------------------------------------------------
extern "C" void kernel_launch(void* const* d_in, const int* in_sizes, int n_in,
                              void* d_out, int out_size, void* d_ws, size_t ws_size,
                              hipStream_t stream) {
  const int*   src = (const int*)  d_in[0];
  const float* W   = (const float*)d_in[1];
  const float* h0  = (const float*)d_in[2];
  const float* Whi = (const float*)d_in[3];
  const float* Whh = (const float*)d_in[4];
  const float* b   = (const float*)d_in[5];
  float* out = (float*)d_out;

  float* U    = (float*)d_ws;                                      // 16 MB
  float* hbuf = (float*)((char*)d_ws + (size_t)SEQ * HID * sizeof(float));  // 16 KB, 4 slots
  // no memset needed: 0xAA-poison (-3.03e-13) and zeros both fail every tag window

  embed_gemm<<<SEQ / BT, 256, 0, stream>>>(src, W, Whi, b, U);
  rnn_seq<<<NWG, 256, 0, stream>>>(Whh, U, h0, out, hbuf);
}